// Round 3
// baseline (200.589 us; speedup 1.0000x reference)
//
#include <hip/hip_runtime.h>

// ROI Align (crop_and_resize-style bilinear), fp32.
// fmaps: [8,128,128,256], rois: [8,128,4] (x1,y1,x2,y2), out: [8,128,7,7,256]
// One wave (64 lanes) = one output pixel; lane = one float4 of channels.
// Pixel/ROI math forced wave-uniform via readfirstlane -> s_load for rois,
// saddr-form corner gathers. Nontemporal output store (write-only, keep L2
// for fmap corners). XCD swizzle: contiguous pixel chunk per XCD for L2 reuse
// of the per-ROI row pairs.

#define NBATCH 8
#define NROI   128
#define FH     128
#define FW     128
#define NC     256
#define OH     7
#define OW     7

typedef float f32x4 __attribute__((ext_vector_type(4)));  // native vec: ok for nontemporal builtins

__global__ __launch_bounds__(256) void roi_align_kernel(
    const float* __restrict__ fmaps,
    const float* __restrict__ rois,
    float* __restrict__ out)
{
    // XCD swizzle: gridDim.x = 12544 = 8 * 1568. Default dispatch round-robins
    // blocks across the 8 XCDs; remap so XCD k gets a contiguous 1568-block
    // (6272-pixel) range -> per-ROI corner-row reuse stays in one L2.
    const int nb8 = gridDim.x >> 3;                 // blocks per XCD chunk
    const int blk = (blockIdx.x & 7) * nb8 + (blockIdx.x >> 3);

    const int lane = threadIdx.x & 63;
    // wave-uniform pixel id (b, roi, i, j flattened)
    const int pix = __builtin_amdgcn_readfirstlane((blk * 256 + (int)threadIdx.x) >> 6);

    const int j   = pix % OW;
    int t         = pix / OW;
    const int i   = t % OH;
    t             = t / OH;
    const int roi = t % NROI;
    const int b   = t / NROI;

    // wave-uniform ROI load -> s_load_dwordx4
    const float* r = rois + (size_t)(b * NROI + roi) * 4;
    const float x1 = r[0], y1 = r[1], x2 = r[2], y2 = r[3];

    const float Hf = 128.0f, Wf = 128.0f;
    // Replicate reference op order exactly: (v * Hf) / (Hf - 1)
    const float by1 = y1 * Hf / (Hf - 1.0f);
    const float bx1 = x1 * Wf / (Wf - 1.0f);
    const float by2 = y2 * Hf / (Hf - 1.0f);
    const float bx2 = x2 * Wf / (Wf - 1.0f);

    float in_y = by1 * (Hf - 1.0f) + (float)i * ((by2 - by1) * (Hf - 1.0f) / 6.0f);
    float in_x = bx1 * (Wf - 1.0f) + (float)j * ((bx2 - bx1) * (Wf - 1.0f) / 6.0f);

    const bool valid = (in_y >= 0.0f) & (in_y <= Hf - 1.0f) &
                       (in_x >= 0.0f) & (in_x <= Wf - 1.0f);

    in_y = fminf(fmaxf(in_y, 0.0f), Hf - 1.0f);
    in_x = fminf(fmaxf(in_x, 0.0f), Wf - 1.0f);

    const float y0f = floorf(in_y);
    const float x0f = floorf(in_x);
    const float ly  = in_y - y0f;
    const float lx  = in_x - x0f;
    const int y0  = (int)y0f;
    const int x0  = (int)x0f;
    const int y1i = min(y0 + 1, FH - 1);
    const int x1i = min(x0 + 1, FW - 1);

    // fmap for this batch, viewed as f32x4: index (y*FW + x)*64 + lane
    const f32x4* __restrict__ f =
        (const f32x4*)(fmaps + (size_t)b * FH * FW * NC);

    const f32x4 tl = f[(y0  * FW + x0 ) * 64 + lane];
    const f32x4 tr = f[(y0  * FW + x1i) * 64 + lane];
    const f32x4 bl = f[(y1i * FW + x0 ) * 64 + lane];
    const f32x4 br = f[(y1i * FW + x1i) * 64 + lane];

    const float m = valid ? 1.0f : 0.0f;

    const f32x4 top = tl + (tr - tl) * lx;
    const f32x4 bot = bl + (br - bl) * lx;
    const f32x4 o   = (top + (bot - top) * ly) * m;

    // write-only output: nontemporal store, don't evict fmap from L2/L3
    f32x4* op = (f32x4*)out + (size_t)pix * 64 + lane;
    __builtin_nontemporal_store(o, op);
}

extern "C" void kernel_launch(void* const* d_in, const int* in_sizes, int n_in,
                              void* d_out, int out_size, void* d_ws, size_t ws_size,
                              hipStream_t stream) {
    const float* fmaps = (const float*)d_in[0];
    const float* rois  = (const float*)d_in[1];
    float* out = (float*)d_out;

    // total f32x4 lanes: 8*128*7*7 pixels * 64 = 3,211,264 -> 12,544 blocks
    const int total = NBATCH * NROI * OH * OW * 64;
    roi_align_kernel<<<total / 256, 256, 0, stream>>>(fmaps, rois, out);
}